// Round 9
// baseline (467.104 us; speedup 1.0000x reference)
//
#include <hip/hip_runtime.h>
#include <hip/hip_cooperative_groups.h>
#include <math.h>

namespace cg = cooperative_groups;

// ---- Problem constants ----
#define B_    128
#define L_    512
#define H_    128
#define NPT_  1023
#define N_    (B_ * NPT_)     // 130944
#define NLEAF (B_ * L_)       // 65536
#define OUT_  128
#define VOCAB 32000

typedef unsigned short ushort_t;
typedef __attribute__((ext_vector_type(8))) __bf16 bf16x8;
typedef __attribute__((ext_vector_type(4))) float f32x4;

__device__ __forceinline__ float sigmoidf_(float x) {
    return 1.0f / (1.0f + __expf(-x));
}
__device__ __forceinline__ float tanhf_(float x) {
    return 1.0f - 2.0f / (__expf(2.0f * x) + 1.0f);
}
__device__ __forceinline__ ushort_t f2bf(float f) {
    unsigned u = __float_as_uint(f);
    return (ushort_t)((u + 0x7fffu + ((u >> 16) & 1u)) >> 16);
}
__device__ __forceinline__ float bf2f(ushort_t s) {
    return __uint_as_float(((unsigned)s) << 16);
}

// =====================================================================
// Prep (fused): weights -> bf16 transposed, emb -> bf16.
// =====================================================================
__global__ __launch_bounds__(256)
void prep_fused(const float* __restrict__ W_iou,
                const float* __restrict__ U_iou,
                const float* __restrict__ U_f_w,
                const float* __restrict__ emb,
                ushort_t* __restrict__ W_iouT,     // [384][128]
                ushort_t* __restrict__ U_catT,     // [640][256]
                ushort_t* __restrict__ embb) {     // [VOCAB][128]
    int idx = blockIdx.x * 256 + threadIdx.x;
    if (idx < VOCAB * H_ / 8) {
        int e0 = idx * 8;
        f32x4 f0 = *(const f32x4*)(emb + e0);
        f32x4 f1 = *(const f32x4*)(emb + e0 + 4);
        union { bf16x8 v; ushort_t e[8]; } p;
        p.e[0] = f2bf(f0[0]); p.e[1] = f2bf(f0[1]);
        p.e[2] = f2bf(f0[2]); p.e[3] = f2bf(f0[3]);
        p.e[4] = f2bf(f1[0]); p.e[5] = f2bf(f1[1]);
        p.e[6] = f2bf(f1[2]); p.e[7] = f2bf(f1[3]);
        *(bf16x8*)(embb + e0) = p.v;
    }
    if (idx < 640 * 256) {
        int n = idx >> 8, k = idx & 255;
        float v = (n < 384) ? U_iou[k * 384 + n] : U_f_w[k * 256 + (n - 384)];
        U_catT[idx] = f2bf(v);
    }
    if (idx < 384 * 128) {
        int n = idx >> 7, k = idx & 127;
        W_iouT[idx] = f2bf(W_iou[k * 384 + n]);
    }
}

// =====================================================================
// Leaf (B register-resident, r8-verified): wave = gate group gg; B slice
// loaded once; grid-stride over M-tiles of 16 leaves.
// =====================================================================
__global__ __launch_bounds__(256, 4)
void leaf_v3(const int* __restrict__ label,
             const ushort_t* __restrict__ embb,
             const ushort_t* __restrict__ WT,
             const float* __restrict__ b_iou,
             ushort_t* __restrict__ h,
             float* __restrict__ c,
             int ntiles, int stripes) {
    const int tid  = threadIdx.x;
    const int lane = tid & 63;
    const int wave = tid >> 6;
    const int li   = lane & 15;
    const int q    = lane >> 4;
    const int q8   = q << 3;
    const int gg   = blockIdx.y * 4 + wave;
    const int j    = gg * 16 + li;

    bf16x8 Bf[3][4];
    #pragma unroll
    for (int t = 0; t < 3; ++t) {
        const ushort_t* bp = WT + (size_t)(16 * (gg + 8 * t) + li) * 128 + q8;
        #pragma unroll
        for (int kt = 0; kt < 4; ++kt) Bf[t][kt] = *(const bf16x8*)(bp + kt * 32);
    }

    const float bi = b_iou[j], bo = b_iou[128 + j], bu = b_iou[256 + j];

    for (int tile = blockIdx.x; tile < ntiles; tile += stripes) {
        const int i0 = tile * 16;
        int ia = i0 + li, ba = ia >> 9, pa = ia & 511;
        const ushort_t* pA = embb + (size_t)label[ba * NPT_ + pa] * H_;
        bf16x8 a[4];
        #pragma unroll
        for (int kt = 0; kt < 4; ++kt) a[kt] = *(const bf16x8*)(pA + kt * 32 + q8);

        f32x4 acc[3];
        #pragma unroll
        for (int t = 0; t < 3; ++t) acc[t] = (f32x4){0.f, 0.f, 0.f, 0.f};
        #pragma unroll
        for (int kt = 0; kt < 4; ++kt)
            #pragma unroll
            for (int t = 0; t < 3; ++t)
                acc[t] = __builtin_amdgcn_mfma_f32_16x16x32_bf16(a[kt], Bf[t][kt], acc[t], 0, 0, 0);

        #pragma unroll
        for (int r = 0; r < 4; ++r) {
            int m  = i0 + q * 4 + r;
            int b  = m >> 9, pos = m & 511;
            size_t gn = (size_t)(b * NPT_ + pos) * H_ + j;
            float iv = sigmoidf_(acc[0][r] + bi);
            float ov = sigmoidf_(acc[1][r] + bo);
            float uv = tanhf_(acc[2][r] + bu);
            float cv = iv * uv;
            float hv = ov * tanhf_(cv);
            c[gn] = cv;
            h[gn] = f2bf(hv);
        }
    }
}

// =====================================================================
// Cooperative mega-kernel: all 9 levels + root, grid.sync() between
// levels. Wave's gate-group B slice (40 frags, 160 VGPR) loaded ONCE
// and reused across ALL levels. gg = wid&7 (NW multiple of 8).
// =====================================================================
__global__ __launch_bounds__(256, 2)
void levels_coop(const ushort_t* __restrict__ Ucat,
                 const float* __restrict__ b_iou,
                 const float* __restrict__ U_f_b,
                 ushort_t* __restrict__ h,
                 float* __restrict__ c,
                 const float* __restrict__ W_out,
                 const float* __restrict__ b_out,
                 float* __restrict__ out) {
    cg::grid_group grid = cg::this_grid();
    const int tid  = threadIdx.x;
    const int lane = tid & 63;
    const int wave = tid >> 6;
    const int li   = lane & 15;
    const int q    = lane >> 4;
    const int q8   = q << 3;
    const int wid  = blockIdx.x * 4 + wave;
    const int NW   = gridDim.x * 4;
    const int gg   = wid & 7;
    const int ws0  = wid >> 3;
    const int nstripe = NW >> 3;
    const int j    = gg * 16 + li;

    // B once, resident for the whole kernel
    bf16x8 Bf[5][8];
    #pragma unroll
    for (int t = 0; t < 5; ++t) {
        const ushort_t* bp = Ucat + (size_t)(16 * (gg + 8 * t) + li) * 256 + q8;
        #pragma unroll
        for (int kt = 0; kt < 8; ++kt) Bf[t][kt] = *(const bf16x8*)(bp + kt * 32);
    }

    const float bi  = b_iou[j], bo = b_iou[128 + j], bu = b_iou[256 + j];
    const float bfl = U_f_b[j], bfr = U_f_b[128 + j];

    int child = 0, node = 512, cnt = 256, lc = 8;
    for (int lvl = 0; lvl < 9; ++lvl) {
        const int mask   = (1 << lc) - 1;
        const int ntiles = (B_ * cnt) >> 4;
        for (int tile = ws0; tile < ntiles; tile += nstripe) {
            const int i0 = tile * 16;

            // epilogue c-children prefetch (hides under K-loop)
            float clv[4], crv[4];
            int   gnrow[4];
            #pragma unroll
            for (int r = 0; r < 4; ++r) {
                int m = i0 + q * 4 + r;
                int b = m >> lc, pos = m & mask;
                int gl = b * NPT_ + child + 2 * pos;
                gnrow[r] = b * NPT_ + node + pos;
                clv[r] = c[(size_t)gl * H_ + j];
                crv[r] = c[(size_t)(gl + 1) * H_ + j];
            }

            // A: 16 h_cat rows; kt<4 left child, kt>=4 right child
            int ia = i0 + li, ba = ia >> lc, pa = ia & mask;
            int gl0 = ba * NPT_ + child + 2 * pa;
            const ushort_t* pl = h + (size_t)gl0 * H_;
            const ushort_t* pr = h + (size_t)(gl0 + 1) * H_;
            bf16x8 a[8];
            #pragma unroll
            for (int kt = 0; kt < 8; ++kt) {
                const ushort_t* p = (kt < 4) ? pl : pr;
                a[kt] = *(const bf16x8*)(p + (kt & 3) * 32 + q8);
            }

            f32x4 acc[5];
            #pragma unroll
            for (int t = 0; t < 5; ++t) acc[t] = (f32x4){0.f, 0.f, 0.f, 0.f};
            #pragma unroll
            for (int kt = 0; kt < 8; ++kt)
                #pragma unroll
                for (int t = 0; t < 5; ++t)
                    acc[t] = __builtin_amdgcn_mfma_f32_16x16x32_bf16(a[kt], Bf[t][kt], acc[t], 0, 0, 0);

            #pragma unroll
            for (int r = 0; r < 4; ++r) {
                size_t gn = (size_t)gnrow[r] * H_ + j;
                float iv = sigmoidf_(acc[0][r] + bi);
                float ov = sigmoidf_(acc[1][r] + bo);
                float uv = tanhf_(acc[2][r] + bu);
                float fl = sigmoidf_(acc[3][r] + bfl);
                float fr = sigmoidf_(acc[4][r] + bfr);
                float cv = iv * uv + fl * clv[r] + fr * crv[r];
                float hv = ov * tanhf_(cv);
                c[gn] = cv;
                h[gn] = f2bf(hv);
            }
        }
        grid.sync();
        child = node; node += cnt; cnt >>= 1; --lc;
    }

    // ---- root phase: block b < 128 handles tree b ----
    if (blockIdx.x < B_) {
        __shared__ float e[H_];
        __shared__ float red[128];
        const int b = blockIdx.x;
        const size_t g = (size_t)(b * NPT_ + (NPT_ - 1)) * H_;

        if (tid < 128) e[tid] = bf2f(h[g + tid]);
        __syncthreads();

        float acc = 0.0f;
        if (tid < 128) {
            acc = b_out[tid];
            for (int k = 0; k < H_; ++k)
                acc += e[k] * W_out[k * OUT_ + tid];
            red[tid] = acc;
        }
        __syncthreads();
        for (int s = 64; s > 0; s >>= 1) {
            if (tid < s) red[tid] = fmaxf(red[tid], red[tid + s]);
            __syncthreads();
        }
        float mx = red[0];
        __syncthreads();
        if (tid < 128) red[tid] = expf(acc - mx);
        __syncthreads();
        for (int s = 64; s > 0; s >>= 1) {
            if (tid < s) red[tid] += red[tid + s];
            __syncthreads();
        }
        float lse = logf(red[0]);
        if (tid < 128) out[b * OUT_ + tid] = acc - mx - lse;
    }
}

// =====================================================================
// Fallback (non-cooperative) level + root kernels — r8-verified.
// =====================================================================
__global__ __launch_bounds__(256, 2)
void level_v3(const ushort_t* __restrict__ Ucat,
              const float* __restrict__ b_iou,
              const float* __restrict__ U_f_b,
              ushort_t* __restrict__ h,
              float* __restrict__ c,
              int node_base, int child_base, int lc,
              int ntiles, int stripes) {
    const int tid  = threadIdx.x;
    const int lane = tid & 63;
    const int wave = tid >> 6;
    const int li   = lane & 15;
    const int q    = lane >> 4;
    const int q8   = q << 3;
    const int mask = (1 << lc) - 1;
    const int gg   = blockIdx.y * 4 + wave;
    const int j    = gg * 16 + li;

    bf16x8 Bf[5][8];
    #pragma unroll
    for (int t = 0; t < 5; ++t) {
        const ushort_t* bp = Ucat + (size_t)(16 * (gg + 8 * t) + li) * 256 + q8;
        #pragma unroll
        for (int kt = 0; kt < 8; ++kt) Bf[t][kt] = *(const bf16x8*)(bp + kt * 32);
    }

    const float bi  = b_iou[j], bo = b_iou[128 + j], bu = b_iou[256 + j];
    const float bfl = U_f_b[j], bfr = U_f_b[128 + j];

    for (int tile = blockIdx.x; tile < ntiles; tile += stripes) {
        const int i0 = tile * 16;
        float clv[4], crv[4];
        int   gnrow[4];
        #pragma unroll
        for (int r = 0; r < 4; ++r) {
            int m = i0 + q * 4 + r;
            int b = m >> lc, pos = m & mask;
            int gl = b * NPT_ + child_base + 2 * pos;
            gnrow[r] = b * NPT_ + node_base + pos;
            clv[r] = c[(size_t)gl * H_ + j];
            crv[r] = c[(size_t)(gl + 1) * H_ + j];
        }
        int ia = i0 + li, ba = ia >> lc, pa = ia & mask;
        int gl0 = ba * NPT_ + child_base + 2 * pa;
        const ushort_t* pl = h + (size_t)gl0 * H_;
        const ushort_t* pr = h + (size_t)(gl0 + 1) * H_;
        bf16x8 a[8];
        #pragma unroll
        for (int kt = 0; kt < 8; ++kt) {
            const ushort_t* p = (kt < 4) ? pl : pr;
            a[kt] = *(const bf16x8*)(p + (kt & 3) * 32 + q8);
        }
        f32x4 acc[5];
        #pragma unroll
        for (int t = 0; t < 5; ++t) acc[t] = (f32x4){0.f, 0.f, 0.f, 0.f};
        #pragma unroll
        for (int kt = 0; kt < 8; ++kt)
            #pragma unroll
            for (int t = 0; t < 5; ++t)
                acc[t] = __builtin_amdgcn_mfma_f32_16x16x32_bf16(a[kt], Bf[t][kt], acc[t], 0, 0, 0);
        #pragma unroll
        for (int r = 0; r < 4; ++r) {
            size_t gn = (size_t)gnrow[r] * H_ + j;
            float iv = sigmoidf_(acc[0][r] + bi);
            float ov = sigmoidf_(acc[1][r] + bo);
            float uv = tanhf_(acc[2][r] + bu);
            float fl = sigmoidf_(acc[3][r] + bfl);
            float fr = sigmoidf_(acc[4][r] + bfr);
            float cv = iv * uv + fl * clv[r] + fr * crv[r];
            float hv = ov * tanhf_(cv);
            c[gn] = cv;
            h[gn] = f2bf(hv);
        }
    }
}

__global__ __launch_bounds__(128)
void root_kernel(const ushort_t* __restrict__ h,
                 const float* __restrict__ W_out,
                 const float* __restrict__ b_out,
                 float* __restrict__ out) {
    __shared__ float e[H_];
    __shared__ float red[128];
    const int j = threadIdx.x;
    const int b = blockIdx.x;
    const size_t g = (size_t)(b * NPT_ + (NPT_ - 1)) * H_;

    e[j] = bf2f(h[g + j]);
    __syncthreads();
    float acc = b_out[j];
    for (int k = 0; k < H_; ++k)
        acc += e[k] * W_out[k * OUT_ + j];
    red[j] = acc; __syncthreads();
    #pragma unroll
    for (int s = 64; s > 0; s >>= 1) {
        if (j < s) red[j] = fmaxf(red[j], red[j + s]);
        __syncthreads();
    }
    float mx = red[0]; __syncthreads();
    red[j] = expf(acc - mx); __syncthreads();
    #pragma unroll
    for (int s = 64; s > 0; s >>= 1) {
        if (j < s) red[j] += red[j + s];
        __syncthreads();
    }
    float lse = logf(red[0]);
    out[b * OUT_ + j] = acc - mx - lse;
}

// =====================================================================
extern "C" void kernel_launch(void* const* d_in, const int* in_sizes, int n_in,
                              void* d_out, int out_size, void* d_ws, size_t ws_size,
                              hipStream_t stream) {
    const int*   label = (const int*)d_in[0];
    const float* emb   = (const float*)d_in[1];
    const float* W_iou = (const float*)d_in[2];
    const float* U_iou = (const float*)d_in[3];
    const float* b_iou = (const float*)d_in[4];
    const float* U_f_w = (const float*)d_in[5];
    const float* U_f_b = (const float*)d_in[6];
    const float* W_out = (const float*)d_in[7];
    const float* b_out = (const float*)d_in[8];
    float* outp = (float*)d_out;

    float*    c    = (float*)d_ws;
    ushort_t* h    = (ushort_t*)(c + (size_t)N_ * H_);
    ushort_t* Ucat = h + (size_t)N_ * H_;
    ushort_t* WT   = Ucat + 640 * 256;
    ushort_t* embb = WT + 384 * 128;

    prep_fused<<<2000, 256, 0, stream>>>(W_iou, U_iou, U_f_w, emb, WT, Ucat, embb);

    {   // leaf: 4096 M-tiles of 16; 512 stripes x 2 group-halves
        int ntiles = NLEAF / 16, stripes = 512;
        leaf_v3<<<dim3(stripes, 2), 256, 0, stream>>>(
            label, embb, WT, b_iou, h, c, ntiles, stripes);
    }

    // cooperative mega-kernel for all levels + root
    int nb = 0;
    hipOccupancyMaxActiveBlocksPerMultiprocessor(&nb, levels_coop, 256, 0);
    if (nb < 1) nb = 1;
    int grid = nb * 256;
    if (grid > 512) grid = 512;

    void* args[] = {(void*)&Ucat, (void*)&b_iou, (void*)&U_f_b, (void*)&h,
                    (void*)&c, (void*)&W_out, (void*)&b_out, (void*)&outp};
    hipError_t err = hipLaunchCooperativeKernel(levels_coop, dim3(grid), dim3(256),
                                                args, 0, stream);
    if (err != hipSuccess) {
        (void)hipGetLastError();   // clear; fall back to per-level launches
        int child = 0, node = 512, cnt = 256, lc = 8;
        for (int lvl = 0; lvl < 9; ++lvl) {
            int rows = B_ * cnt;
            int ntiles  = rows / 16;
            int stripes = ntiles < 256 ? ntiles : 256;
            level_v3<<<dim3(stripes, 2), 256, 0, stream>>>(
                Ucat, b_iou, U_f_b, h, c, node, child, lc, ntiles, stripes);
            child = node; node += cnt; cnt >>= 1; --lc;
        }
        root_kernel<<<B_, 128, 0, stream>>>(h, W_out, b_out, outp);
    }
}

// Round 10
// 221.911 us; speedup vs baseline: 2.1049x; 2.1049x over previous
//
#include <hip/hip_runtime.h>
#include <math.h>

// ---- Problem constants ----
#define B_    128
#define L_    512
#define H_    128
#define NPT_  1023
#define N_    (B_ * NPT_)     // 130944
#define NLEAF (B_ * L_)       // 65536
#define OUT_  128
#define VOCAB 32000
#define TBASE 992             // first tail node (cnt=16 level base)

typedef unsigned short ushort_t;
typedef __attribute__((ext_vector_type(8))) __bf16 bf16x8;
typedef __attribute__((ext_vector_type(4))) float f32x4;

__device__ __forceinline__ float sigmoidf_(float x) {
    return 1.0f / (1.0f + __expf(-x));
}
__device__ __forceinline__ float tanhf_(float x) {
    return 1.0f - 2.0f / (__expf(2.0f * x) + 1.0f);
}
__device__ __forceinline__ ushort_t f2bf(float f) {
    unsigned u = __float_as_uint(f);
    return (ushort_t)((u + 0x7fffu + ((u >> 16) & 1u)) >> 16);
}
__device__ __forceinline__ float bf2f(ushort_t s) {
    return __uint_as_float(((unsigned)s) << 16);
}

// =====================================================================
// Prep (fused): weights -> bf16 transposed, emb -> bf16.
// =====================================================================
__global__ __launch_bounds__(256)
void prep_fused(const float* __restrict__ W_iou,
                const float* __restrict__ U_iou,
                const float* __restrict__ U_f_w,
                const float* __restrict__ emb,
                ushort_t* __restrict__ W_iouT,     // [384][128]
                ushort_t* __restrict__ U_catT,     // [640][256]
                ushort_t* __restrict__ embb) {     // [VOCAB][128]
    int idx = blockIdx.x * 256 + threadIdx.x;
    if (idx < VOCAB * H_ / 8) {
        int e0 = idx * 8;
        f32x4 f0 = *(const f32x4*)(emb + e0);
        f32x4 f1 = *(const f32x4*)(emb + e0 + 4);
        union { bf16x8 v; ushort_t e[8]; } p;
        p.e[0] = f2bf(f0[0]); p.e[1] = f2bf(f0[1]);
        p.e[2] = f2bf(f0[2]); p.e[3] = f2bf(f0[3]);
        p.e[4] = f2bf(f1[0]); p.e[5] = f2bf(f1[1]);
        p.e[6] = f2bf(f1[2]); p.e[7] = f2bf(f1[3]);
        *(bf16x8*)(embb + e0) = p.v;
    }
    if (idx < 640 * 256) {
        int n = idx >> 8, k = idx & 255;
        float v = (n < 384) ? U_iou[k * 384 + n] : U_f_w[k * 256 + (n - 384)];
        U_catT[idx] = f2bf(v);
    }
    if (idx < 384 * 128) {
        int n = idx >> 7, k = idx & 127;
        W_iouT[idx] = f2bf(W_iou[k * 384 + n]);
    }
}

// =====================================================================
// Leaf (B register-resident, r8-verified).
// =====================================================================
__global__ __launch_bounds__(256, 4)
void leaf_v3(const int* __restrict__ label,
             const ushort_t* __restrict__ embb,
             const ushort_t* __restrict__ WT,
             const float* __restrict__ b_iou,
             ushort_t* __restrict__ h,
             float* __restrict__ c,
             int ntiles, int stripes) {
    const int tid  = threadIdx.x;
    const int lane = tid & 63;
    const int wave = tid >> 6;
    const int li   = lane & 15;
    const int q    = lane >> 4;
    const int q8   = q << 3;
    const int gg   = blockIdx.y * 4 + wave;
    const int j    = gg * 16 + li;

    bf16x8 Bf[3][4];
    #pragma unroll
    for (int t = 0; t < 3; ++t) {
        const ushort_t* bp = WT + (size_t)(16 * (gg + 8 * t) + li) * 128 + q8;
        #pragma unroll
        for (int kt = 0; kt < 4; ++kt) Bf[t][kt] = *(const bf16x8*)(bp + kt * 32);
    }

    const float bi = b_iou[j], bo = b_iou[128 + j], bu = b_iou[256 + j];

    for (int tile = blockIdx.x; tile < ntiles; tile += stripes) {
        const int i0 = tile * 16;
        int ia = i0 + li, ba = ia >> 9, pa = ia & 511;
        const ushort_t* pA = embb + (size_t)label[ba * NPT_ + pa] * H_;
        bf16x8 a[4];
        #pragma unroll
        for (int kt = 0; kt < 4; ++kt) a[kt] = *(const bf16x8*)(pA + kt * 32 + q8);

        f32x4 acc[3];
        #pragma unroll
        for (int t = 0; t < 3; ++t) acc[t] = (f32x4){0.f, 0.f, 0.f, 0.f};
        #pragma unroll
        for (int kt = 0; kt < 4; ++kt)
            #pragma unroll
            for (int t = 0; t < 3; ++t)
                acc[t] = __builtin_amdgcn_mfma_f32_16x16x32_bf16(a[kt], Bf[t][kt], acc[t], 0, 0, 0);

        #pragma unroll
        for (int r = 0; r < 4; ++r) {
            int m  = i0 + q * 4 + r;
            int b  = m >> 9, pos = m & 511;
            size_t gn = (size_t)(b * NPT_ + pos) * H_ + j;
            float iv = sigmoidf_(acc[0][r] + bi);
            float ov = sigmoidf_(acc[1][r] + bo);
            float uv = tanhf_(acc[2][r] + bu);
            float cv = iv * uv;
            float hv = ov * tanhf_(cv);
            c[gn] = cv;
            h[gn] = f2bf(hv);
        }
    }
}

// =====================================================================
// Level (B register-resident, r8-verified) — used for cnt >= 32.
// =====================================================================
__global__ __launch_bounds__(256, 2)
void level_v3(const ushort_t* __restrict__ Ucat,
              const float* __restrict__ b_iou,
              const float* __restrict__ U_f_b,
              ushort_t* __restrict__ h,
              float* __restrict__ c,
              int node_base, int child_base, int lc,
              int ntiles, int stripes) {
    const int tid  = threadIdx.x;
    const int lane = tid & 63;
    const int wave = tid >> 6;
    const int li   = lane & 15;
    const int q    = lane >> 4;
    const int q8   = q << 3;
    const int mask = (1 << lc) - 1;
    const int gg   = blockIdx.y * 4 + wave;
    const int j    = gg * 16 + li;

    bf16x8 Bf[5][8];
    #pragma unroll
    for (int t = 0; t < 5; ++t) {
        const ushort_t* bp = Ucat + (size_t)(16 * (gg + 8 * t) + li) * 256 + q8;
        #pragma unroll
        for (int kt = 0; kt < 8; ++kt) Bf[t][kt] = *(const bf16x8*)(bp + kt * 32);
    }

    const float bi  = b_iou[j], bo = b_iou[128 + j], bu = b_iou[256 + j];
    const float bfl = U_f_b[j], bfr = U_f_b[128 + j];

    for (int tile = blockIdx.x; tile < ntiles; tile += stripes) {
        const int i0 = tile * 16;
        float clv[4], crv[4];
        int   gnrow[4];
        #pragma unroll
        for (int r = 0; r < 4; ++r) {
            int m = i0 + q * 4 + r;
            int b = m >> lc, pos = m & mask;
            int gl = b * NPT_ + child_base + 2 * pos;
            gnrow[r] = b * NPT_ + node_base + pos;
            clv[r] = c[(size_t)gl * H_ + j];
            crv[r] = c[(size_t)(gl + 1) * H_ + j];
        }
        int ia = i0 + li, ba = ia >> lc, pa = ia & mask;
        int gl0 = ba * NPT_ + child_base + 2 * pa;
        const ushort_t* pl = h + (size_t)gl0 * H_;
        const ushort_t* pr = h + (size_t)(gl0 + 1) * H_;
        bf16x8 a[8];
        #pragma unroll
        for (int kt = 0; kt < 8; ++kt) {
            const ushort_t* p = (kt < 4) ? pl : pr;
            a[kt] = *(const bf16x8*)(p + (kt & 3) * 32 + q8);
        }
        f32x4 acc[5];
        #pragma unroll
        for (int t = 0; t < 5; ++t) acc[t] = (f32x4){0.f, 0.f, 0.f, 0.f};
        #pragma unroll
        for (int kt = 0; kt < 8; ++kt)
            #pragma unroll
            for (int t = 0; t < 5; ++t)
                acc[t] = __builtin_amdgcn_mfma_f32_16x16x32_bf16(a[kt], Bf[t][kt], acc[t], 0, 0, 0);
        #pragma unroll
        for (int r = 0; r < 4; ++r) {
            size_t gn = (size_t)gnrow[r] * H_ + j;
            float iv = sigmoidf_(acc[0][r] + bi);
            float ov = sigmoidf_(acc[1][r] + bo);
            float uv = tanhf_(acc[2][r] + bu);
            float fl = sigmoidf_(acc[3][r] + bfl);
            float fr = sigmoidf_(acc[4][r] + bfr);
            float cv = iv * uv + fl * clv[r] + fr * crv[r];
            float hv = ov * tanhf_(cv);
            c[gn] = cv;
            h[gn] = f2bf(hv);
        }
    }
}

// =====================================================================
// Tail: one block (512 thr = 8 waves = 8 gate groups) per TREE.
// Levels cnt=16,8,4,2,1 + root, __syncthreads between levels; tail h/c
// live in LDS (never touch HBM). B slice register-resident once.
// First tail level reads children (cnt=32 level) from global h/c.
// =====================================================================
#define TPAD 132
__global__ __launch_bounds__(512, 2)
void tail_kernel(const ushort_t* __restrict__ Ucat,
                 const float* __restrict__ b_iou,
                 const float* __restrict__ U_f_b,
                 const ushort_t* __restrict__ h,
                 const float* __restrict__ c,
                 const float* __restrict__ W_out,
                 const float* __restrict__ b_out,
                 float* __restrict__ out) {
    __shared__ ushort_t hl[31][TPAD];   // tail h, bf16
    __shared__ float    cl[31][TPAD];   // tail c, f32
    __shared__ float    ev[H_];
    __shared__ float    red[128];

    const int tid  = threadIdx.x;
    const int lane = tid & 63;
    const int wave = tid >> 6;          // 0..7 = gate group
    const int li   = lane & 15;
    const int q    = lane >> 4;
    const int q8   = q << 3;
    const int gg   = wave;
    const int j    = gg * 16 + li;
    const int b    = blockIdx.x;        // tree

    bf16x8 Bf[5][8];
    #pragma unroll
    for (int t = 0; t < 5; ++t) {
        const ushort_t* bp = Ucat + (size_t)(16 * (gg + 8 * t) + li) * 256 + q8;
        #pragma unroll
        for (int kt = 0; kt < 8; ++kt) Bf[t][kt] = *(const bf16x8*)(bp + kt * 32);
    }

    const float bi  = b_iou[j], bo = b_iou[128 + j], bu = b_iou[256 + j];
    const float bfl = U_f_b[j], bfr = U_f_b[128 + j];

    int base = TBASE, child = 960, cnt = 16;
    #pragma unroll
    for (int lvl = 0; lvl < 5; ++lvl) {
        // ---- A fragments (row = li, clamped) ----
        int pos = li < cnt ? li : cnt - 1;
        bf16x8 a[8];
        if (lvl == 0) {
            int gl0 = b * NPT_ + child + 2 * pos;
            const ushort_t* pl = h + (size_t)gl0 * H_;
            const ushort_t* pr = h + (size_t)(gl0 + 1) * H_;
            #pragma unroll
            for (int kt = 0; kt < 8; ++kt) {
                const ushort_t* p = (kt < 4) ? pl : pr;
                a[kt] = *(const bf16x8*)(p + (kt & 3) * 32 + q8);
            }
        } else {
            int tl = (child - TBASE) + 2 * pos;
            #pragma unroll
            for (int kt = 0; kt < 8; ++kt) {
                const ushort_t* p = (kt < 4) ? hl[tl] : hl[tl + 1];
                a[kt] = *(const bf16x8*)(p + (kt & 3) * 32 + q8);
            }
        }

        // ---- epilogue c-children (clamped reads) ----
        float clv[4], crv[4];
        #pragma unroll
        for (int r = 0; r < 4; ++r) {
            int m  = q * 4 + r;
            int pm = m < cnt ? m : cnt - 1;
            if (lvl == 0) {
                int gl = b * NPT_ + child + 2 * pm;
                clv[r] = c[(size_t)gl * H_ + j];
                crv[r] = c[(size_t)(gl + 1) * H_ + j];
            } else {
                int tl = (child - TBASE) + 2 * pm;
                clv[r] = cl[tl][j];
                crv[r] = cl[tl + 1][j];
            }
        }

        f32x4 acc[5];
        #pragma unroll
        for (int t = 0; t < 5; ++t) acc[t] = (f32x4){0.f, 0.f, 0.f, 0.f};
        #pragma unroll
        for (int kt = 0; kt < 8; ++kt)
            #pragma unroll
            for (int t = 0; t < 5; ++t)
                acc[t] = __builtin_amdgcn_mfma_f32_16x16x32_bf16(a[kt], Bf[t][kt], acc[t], 0, 0, 0);

        #pragma unroll
        for (int r = 0; r < 4; ++r) {
            int m = q * 4 + r;
            if (m < cnt) {
                int tl = (base - TBASE) + m;
                float iv = sigmoidf_(acc[0][r] + bi);
                float ov = sigmoidf_(acc[1][r] + bo);
                float uv = tanhf_(acc[2][r] + bu);
                float fl = sigmoidf_(acc[3][r] + bfl);
                float fr = sigmoidf_(acc[4][r] + bfr);
                float cv = iv * uv + fl * clv[r] + fr * crv[r];
                float hv = ov * tanhf_(cv);
                cl[tl][j] = cv;
                hl[tl][j] = f2bf(hv);
            }
        }
        __syncthreads();
        child = base; base += cnt; cnt >>= 1;
    }

    // ---- root: logits = h_root @ W_out + b_out, log_softmax ----
    if (tid < 128) ev[tid] = bf2f(hl[30][tid]);
    __syncthreads();

    float acc = 0.0f;
    if (tid < 128) {
        acc = b_out[tid];
        for (int k = 0; k < H_; ++k)
            acc += ev[k] * W_out[k * OUT_ + tid];
        red[tid] = acc;
    }
    __syncthreads();
    for (int s = 64; s > 0; s >>= 1) {
        if (tid < s) red[tid] = fmaxf(red[tid], red[tid + s]);
        __syncthreads();
    }
    float mx = red[0];
    __syncthreads();
    if (tid < 128) red[tid] = expf(acc - mx);
    __syncthreads();
    for (int s = 64; s > 0; s >>= 1) {
        if (tid < s) red[tid] += red[tid + s];
        __syncthreads();
    }
    float lse = logf(red[0]);
    if (tid < 128) out[b * OUT_ + tid] = acc - mx - lse;
}

// =====================================================================
extern "C" void kernel_launch(void* const* d_in, const int* in_sizes, int n_in,
                              void* d_out, int out_size, void* d_ws, size_t ws_size,
                              hipStream_t stream) {
    const int*   label = (const int*)d_in[0];
    const float* emb   = (const float*)d_in[1];
    const float* W_iou = (const float*)d_in[2];
    const float* U_iou = (const float*)d_in[3];
    const float* b_iou = (const float*)d_in[4];
    const float* U_f_w = (const float*)d_in[5];
    const float* U_f_b = (const float*)d_in[6];
    const float* W_out = (const float*)d_in[7];
    const float* b_out = (const float*)d_in[8];
    float* outp = (float*)d_out;

    float*    c    = (float*)d_ws;
    ushort_t* h    = (ushort_t*)(c + (size_t)N_ * H_);
    ushort_t* Ucat = h + (size_t)N_ * H_;
    ushort_t* WT   = Ucat + 640 * 256;
    ushort_t* embb = WT + 384 * 128;

    prep_fused<<<2000, 256, 0, stream>>>(W_iou, U_iou, U_f_w, emb, WT, Ucat, embb);

    {   // leaf: 4096 M-tiles of 16; 512 stripes x 2 group-halves
        int ntiles = NLEAF / 16, stripes = 512;
        leaf_v3<<<dim3(stripes, 2), 256, 0, stream>>>(
            label, embb, WT, b_iou, h, c, ntiles, stripes);
    }

    // big levels: cnt = 256,128,64,32
    int child = 0, node = 512, cnt = 256, lc = 8;
    for (int lvl = 0; lvl < 4; ++lvl) {
        int ntiles  = (B_ * cnt) / 16;
        int stripes = ntiles < 256 ? ntiles : 256;
        level_v3<<<dim3(stripes, 2), 256, 0, stream>>>(
            Ucat, b_iou, U_f_b, h, c, node, child, lc, ntiles, stripes);
        child = node; node += cnt; cnt >>= 1; --lc;
    }

    // tail: cnt=16..1 + root, one block per tree
    tail_kernel<<<B_, 512, 0, stream>>>(Ucat, b_iou, U_f_b, h, c, W_out, b_out, outp);
}